// Round 10
// baseline (769.461 us; speedup 1.0000x reference)
//
#include <hip/hip_runtime.h>
#include <math.h>

// Problem constants (x: (5,1,256,64,64) f32)
constexpr int NIMG = 5;
constexpr int CCH  = 256;   // channels (both c and d)
constexpr int HWP  = 4096;  // H*W
constexpr int PT   = CCH * HWP;  // elems per image = 1048576

// GEMM tiling: 64 d x 128 p per block, per image. BK=16 double-buffered.
// Micro-tile 4d x 8p (two float4 p-halves), 64+64 accs.
// Per wave-cc LDS reads: x 2xb128 + ws b128 + w2 b128 = 4 reads (~48 cyc).
// Floor: 640 blk x 4 waves x 256 cc x 48 / 256 CU = 51 us at ~10 waves/CU.
constexpr int BD = 64;
constexpr int BP = 128;
constexpr int BK = 16;
constexpr int NSTEP = CCH / BK;   // 16

// Async global->LDS, 16B/lane. LDS dest is wave-uniform base; HW adds lane*16.
__device__ __forceinline__ void gload16(const float* g, float* l) {
    __builtin_amdgcn_global_load_lds(
        (const __attribute__((address_space(1))) unsigned int*)g,
        (__attribute__((address_space(3))) unsigned int*)l, 16, 0, 0);
}

// -----------------------------------------------------------------------------
// Kernel 1 (per image): s[n,d,p] = sum_c x[n,c,p]*(W1+W2)[c,d]
//                       v2[n,d,p] = sum_c x[n,c,p]*W2[c,d]
// ws = w1+w2 is formed once per (c,d) at staging time (same fp32 add as the
// passing versions' per-cc add), fma chain ascending c -> bit-identical math.
// One barrier per K-step: stage(t+1) targets buf^1 which nobody reads during
// step t; w is reg-staged (load early, add+ds_write late); x via gload16.
// -----------------------------------------------------------------------------
__global__ __launch_bounds__(256, 3) void gemm_sv(
    const float* __restrict__ x, const float* __restrict__ w,
    float* __restrict__ s_out, float* __restrict__ v_out)
{
    const int t  = threadIdx.x;
    const int tp = t & 15;   // p-frag: cols tp*4..+3 and 64+tp*4..+3
    const int td = t >> 4;   // d-frag: rows td*4..+3
    const int p0 = blockIdx.x * BP;
    const int d0 = blockIdx.y * BD;
    const int n  = blockIdx.z;
    const float* xn = x + (size_t)n * PT;

    __shared__ float xs [2][BK][BP];  // 2 x 8 KB
    __shared__ float wss[2][BK][BD];  // 2 x 4 KB (w1+w2)
    __shared__ float w2s[2][BK][BD];  // 2 x 4 KB

    float acc_s[4][8] = {};
    float acc_2[4][8] = {};

    const int wv = t >> 6, l = t & 63;
    const int xr = l >> 5, xc = (l & 31) * 4;   // x chunk: 2 rows x 128 floats
    const int wrow = t >> 4, wcol = (t & 15) * 4;  // w stage: 16 rows x 64 cols

    float4 w1r, w2r;  // in-flight w registers for next step

    auto load_w = [&](int c0) {
        w1r = *reinterpret_cast<const float4*>(&w[(size_t)(c0 + wrow) * CCH + d0 + wcol]);
        w2r = *reinterpret_cast<const float4*>(&w[(size_t)(CCH + c0 + wrow) * CCH + d0 + wcol]);
    };
    auto stage_x = [&](int b, int c0) {
        #pragma unroll
        for (int k = 0; k < 2; ++k) {
            const int r0 = (wv + k * 4) * 2;   // chunk base row (2 rows/chunk)
            gload16(&xn[(size_t)(c0 + r0 + xr) * HWP + p0 + xc], &xs[b][r0][0]);
        }
    };
    auto write_w = [&](int b) {
        const float4 wsv = {w1r.x + w2r.x, w1r.y + w2r.y, w1r.z + w2r.z, w1r.w + w2r.w};
        *reinterpret_cast<float4*>(&wss[b][wrow][wcol]) = wsv;
        *reinterpret_cast<float4*>(&w2s[b][wrow][wcol]) = w2r;
    };

    // prologue: fill buffer 0
    load_w(0);
    stage_x(0, 0);
    write_w(0);          // compiler inserts the vmcnt wait for w1r/w2r
    __syncthreads();     // drains x gloads (vmcnt) + ds_writes (lgkm)

    for (int st = 0; st < NSTEP; ++st) {
        const int cur = st & 1;
        const bool more = (st + 1 < NSTEP);
        if (more) {
            load_w((st + 1) * BK);       // VMEM, lands during compute
            stage_x(cur ^ 1, (st + 1) * BK);
        }

        #pragma unroll
        for (int cc = 0; cc < BK; ++cc) {
            const float4 wsv = *reinterpret_cast<const float4*>(&wss[cur][cc][td * 4]);
            const float4 w2v = *reinterpret_cast<const float4*>(&w2s[cur][cc][td * 4]);
            const float4 xv0 = *reinterpret_cast<const float4*>(&xs[cur][cc][tp * 4]);
            const float4 xv1 = *reinterpret_cast<const float4*>(&xs[cur][cc][64 + tp * 4]);
            const float xa [8] = {xv0.x, xv0.y, xv0.z, xv0.w,
                                  xv1.x, xv1.y, xv1.z, xv1.w};
            const float wsa[4] = {wsv.x, wsv.y, wsv.z, wsv.w};
            const float w2a[4] = {w2v.x, w2v.y, w2v.z, w2v.w};
            #pragma unroll
            for (int i = 0; i < 4; ++i) {
                #pragma unroll
                for (int j = 0; j < 8; ++j) {
                    acc_s[i][j] = fmaf(wsa[i], xa[j], acc_s[i][j]);
                    acc_2[i][j] = fmaf(w2a[i], xa[j], acc_2[i][j]);
                }
            }
        }

        if (more) write_w(cur ^ 1);   // w regs arrived during compute
        __syncthreads();              // drains gloads + ds_writes; opens buf^1
    }

    // epilogue: store raw s and v2 (u is formed in the edge kernel)
    #pragma unroll
    for (int i = 0; i < 4; ++i) {
        const size_t base = (size_t)(d0 + td * 4 + i) * HWP + p0 + tp * 4;
        const float4 s0 = {acc_s[i][0], acc_s[i][1], acc_s[i][2], acc_s[i][3]};
        const float4 s1 = {acc_s[i][4], acc_s[i][5], acc_s[i][6], acc_s[i][7]};
        const float4 v0 = {acc_2[i][0], acc_2[i][1], acc_2[i][2], acc_2[i][3]};
        const float4 v1 = {acc_2[i][4], acc_2[i][5], acc_2[i][6], acc_2[i][7]};
        *reinterpret_cast<float4*>(&s_out[(size_t)n * PT + base])      = s0;
        *reinterpret_cast<float4*>(&s_out[(size_t)n * PT + base + 64]) = s1;
        *reinterpret_cast<float4*>(&v_out[(size_t)n * PT + base])      = v0;
        *reinterpret_cast<float4*>(&v_out[(size_t)n * PT + base + 64]) = v1;
    }
}

// -----------------------------------------------------------------------------
// Kernel 2: per-pixel edges. u[n] = (x[n] - s[n]) - b[d] (same fp op order as
// passing versions), v[n] = v2[n]; e[i][j]=|u[j]-v[i]|; row-norm threshold;
// out[i] = sum_j kept_e * x[j]. Math verbatim -> bit-identical.
// -----------------------------------------------------------------------------
__global__ __launch_bounds__(256) void edge_out(
    const float* __restrict__ x, const float* __restrict__ s,
    const float* __restrict__ v2, const float* __restrict__ bias,
    float* __restrict__ out)
{
    const size_t p = ((size_t)blockIdx.x * blockDim.x + threadIdx.x) * 4;
    if (p >= (size_t)PT) return;
    const float bd = bias[p >> 12];   // d = p / 4096 (same for all 4 pixels)

    float xa[NIMG][4], ua[NIMG][4], va[NIMG][4];
    #pragma unroll
    for (int n2 = 0; n2 < NIMG; ++n2) {
        const float4 xv = *reinterpret_cast<const float4*>(&x [(size_t)n2 * PT + p]);
        const float4 sv = *reinterpret_cast<const float4*>(&s [(size_t)n2 * PT + p]);
        const float4 vv = *reinterpret_cast<const float4*>(&v2[(size_t)n2 * PT + p]);
        const float xt[4] = {xv.x, xv.y, xv.z, xv.w};
        const float st[4] = {sv.x, sv.y, sv.z, sv.w};
        const float vt[4] = {vv.x, vv.y, vv.z, vv.w};
        #pragma unroll
        for (int q = 0; q < 4; ++q) {
            xa[n2][q] = xt[q];
            ua[n2][q] = (xt[q] - st[q]) - bd;
            va[n2][q] = vt[q];
        }
    }

    float oacc[NIMG][4];
    #pragma unroll
    for (int q = 0; q < 4; ++q) {
        #pragma unroll
        for (int i = 0; i < NIMG; ++i) {
            float e[NIMG];
            float sumsq = 0.0f;
            #pragma unroll
            for (int j = 0; j < NIMG; ++j) {
                e[j] = fabsf(ua[j][q] - va[i][q]);
                sumsq = fmaf(e[j], e[j], sumsq);
            }
            const float m = fmaxf(sqrtf(sumsq), 1e-12f);
            float h = 0.0f;
            #pragma unroll
            for (int j = 0; j < NIMG; ++j) {
                const float en = e[j] / m;
                if (en > 0.35f) h = fmaf(e[j], xa[j][q], h);
            }
            oacc[i][q] = h;
        }
    }

    #pragma unroll
    for (int i = 0; i < NIMG; ++i) {
        const float4 ov = {oacc[i][0], oacc[i][1], oacc[i][2], oacc[i][3]};
        *reinterpret_cast<float4*>(&out[(size_t)i * PT + p]) = ov;
    }
}

extern "C" void kernel_launch(void* const* d_in, const int* in_sizes, int n_in,
                              void* d_out, int out_size, void* d_ws, size_t ws_size,
                              hipStream_t stream) {
    const float* x    = (const float*)d_in[0];
    const float* w    = (const float*)d_in[1];
    const float* bias = (const float*)d_in[2];
    float* out = (float*)d_out;

    float* s  = (float*)d_ws;                      // 20 MB
    float* v2 = s + (size_t)NIMG * PT;             // 20 MB

    dim3 g1(HWP / BP, CCH / BD, NIMG);             // 32 x 4 x 5 = 640 blocks
    gemm_sv<<<g1, 256, 0, stream>>>(x, w, s, v2);

    const int n4 = PT / 4;                         // 262144 pixel-quads
    edge_out<<<(n4 + 255) / 256, 256, 0, stream>>>(x, s, v2, bias, out);
}

// Round 11
// 652.843 us; speedup vs baseline: 1.1786x; 1.1786x over previous
//
#include <hip/hip_runtime.h>
#include <math.h>

// Problem constants (x: (5,1,256,64,64) f32)
constexpr int NIMG = 5;
constexpr int CCH  = 256;   // channels (both c and d)
constexpr int HWP  = 4096;  // H*W
constexpr int PT   = CCH * HWP;  // elems per image = 1048576

// Tiling (R5-proven shape): 32 d x 64 p per block, K-step 16, n-loop in block.
// Micro-tile 2d x 4p x 5 images dual-acc = 80 acc regs (104 VGPR, no spill).
// NEW vs R5: TRIPLE-buffered LDS (72 KB, 2 blocks/CU) -> ONE barrier per
// K-step (was 2) and 2-step prefetch depth with counted vmcnt(6).
constexpr int BD = 32;
constexpr int BP = 64;
constexpr int BK = 16;
constexpr int NSTEP = CCH / BK;   // 16

// Async global->LDS, 16B/lane. LDS dest is wave-uniform base; HW adds lane*16.
__device__ __forceinline__ void gload16(const float* g, float* l) {
    __builtin_amdgcn_global_load_lds(
        (const __attribute__((address_space(1))) unsigned int*)g,
        (__attribute__((address_space(3))) unsigned int*)l, 16, 0, 0);
}

// -----------------------------------------------------------------------------
// Fully fused kernel (math chain verbatim from the passing 82.8us version):
//   acc_s[n] = sum_c x[n,c,p]*(W1+W2)[c,d]   (wsa = w1+w2 formed per cc)
//   acc_2[n] = sum_c x[n,c,p]*W2[c,d]
//   u = x - acc_s - b ; v = acc_2 ; e=|u[j]-v[i]| ; row-norm threshold;
//   out[i] = sum_j kept_e * x[j].
// Pipeline: stage(st) waited via per-wave vmcnt(6) at top of iter st (steps
// st+1, st+2 = 12 loads stay in flight; vmcnt waits oldest-first), single
// s_barrier, compute buf st%3, then stage(st+2) into buf (st+2)%3 (never
// concurrently read: barrier(st) separates it from compute(st-1) which used
// the same mod-3 buffer, and compute(st) uses a different one).
// -----------------------------------------------------------------------------
__global__ __launch_bounds__(256, 2) void fused_all(
    const float* __restrict__ x, const float* __restrict__ w,
    const float* __restrict__ bias, float* __restrict__ out)
{
    const int t  = threadIdx.x;
    const int tp = t & 15;   // p-frag: cols p0 + tp*4 .. +3
    const int td = t >> 4;   // d-frag: rows d0 + td*2, td*2+1
    const int p0 = blockIdx.x * BP;
    const int d0 = blockIdx.y * BD;

    __shared__ float xs [3][NIMG][BK][BP];  // 3 x 20 KB
    __shared__ float w1s[3][BK][BD];        // 3 x 2 KB
    __shared__ float w2s[3][BK][BD];        // 3 x 2 KB

    float acc_s[NIMG][2][4] = {};  // sum_c x*(W1+W2)
    float acc_2[NIMG][2][4] = {};  // sum_c x*W2

    const int wv = t >> 6, l = t & 63;
    const int xr = l >> 4, xc = (l & 15) * 4;  // x chunk: 4 rows x 64 floats
    const int wr = l >> 3, wc = (l & 7) * 4;   // w chunk: 8 rows x 32 floats

    // Stage one K-step into buffer b. 6 gload16 per wave, uniform dests:
    //  - 5 x-chunks: chunk id g = wv + 4s (s=0..4) -> n = g>>2, k = g&3
    //  - 1 w-chunk : wv<2 -> w1 chunk wv ; else w2 chunk wv-2
    auto stage = [&](int b, int c0) {
        #pragma unroll
        for (int s = 0; s < NIMG; ++s) {
            const int g = wv + 4 * s;
            const int n = g >> 2, k = g & 3;
            gload16(&x[(size_t)n * PT + (size_t)(c0 + k * 4 + xr) * HWP + p0 + xc],
                    &xs[b][n][k * 4][0]);
        }
        if (wv < 2) {
            gload16(&w[(size_t)(c0 + wv * 8 + wr) * CCH + d0 + wc],
                    &w1s[b][wv * 8][0]);
        } else {
            gload16(&w[(size_t)(256 + c0 + (wv - 2) * 8 + wr) * CCH + d0 + wc],
                    &w2s[b][(wv - 2) * 8][0]);
        }
    };

    stage(0, 0);
    stage(1, BK);

    for (int st = 0; st < NSTEP; ++st) {
        // wait for step st's own 6 loads (oldest); st+1/st+2 stay in flight
        if (st + 1 < NSTEP) asm volatile("s_waitcnt vmcnt(6)" ::: "memory");
        else                asm volatile("s_waitcnt vmcnt(0)" ::: "memory");
        __builtin_amdgcn_s_barrier();   // buffer st%3 staged in all waves

        const int bsel = st % 3;
        #pragma unroll
        for (int cc = 0; cc < BK; ++cc) {
            const float2 w1v = *reinterpret_cast<const float2*>(&w1s[bsel][cc][td * 2]);
            const float2 w2v = *reinterpret_cast<const float2*>(&w2s[bsel][cc][td * 2]);
            const float w2a[2] = {w2v.x, w2v.y};
            const float wsa[2] = {w1v.x + w2v.x, w1v.y + w2v.y};
            #pragma unroll
            for (int n = 0; n < NIMG; ++n) {
                const float4 xv = *reinterpret_cast<const float4*>(&xs[bsel][n][cc][tp * 4]);
                const float xa[4] = {xv.x, xv.y, xv.z, xv.w};
                #pragma unroll
                for (int i = 0; i < 2; ++i) {
                    #pragma unroll
                    for (int j = 0; j < 4; ++j) {
                        acc_s[n][i][j] = fmaf(wsa[i], xa[j], acc_s[n][i][j]);
                        acc_2[n][i][j] = fmaf(w2a[i], xa[j], acc_2[n][i][j]);
                    }
                }
            }
        }

        if (st + 2 < NSTEP) stage((st + 2) % 3, (st + 2) * BK);
    }

    // ---------------- fused epilogue: edges + threshold + reduce ----------------
    #pragma unroll
    for (int r = 0; r < 2; ++r) {
        const int d = d0 + td * 2 + r;
        const float bd = bias[d];
        const size_t base = (size_t)d * HWP + p0 + tp * 4;

        float xa[NIMG][4], ua[NIMG][4], va[NIMG][4];
        #pragma unroll
        for (int n = 0; n < NIMG; ++n) {
            const float4 xv = *reinterpret_cast<const float4*>(&x[(size_t)n * PT + base]);
            const float xt[4] = {xv.x, xv.y, xv.z, xv.w};
            #pragma unroll
            for (int q = 0; q < 4; ++q) {
                xa[n][q] = xt[q];
                ua[n][q] = xt[q] - acc_s[n][r][q] - bd;
                va[n][q] = acc_2[n][r][q];
            }
        }

        #pragma unroll
        for (int i = 0; i < NIMG; ++i) {
            float ho[4];
            #pragma unroll
            for (int q = 0; q < 4; ++q) {
                float e[NIMG];
                float sumsq = 0.0f;
                #pragma unroll
                for (int j = 0; j < NIMG; ++j) {
                    e[j] = fabsf(ua[j][q] - va[i][q]);
                    sumsq = fmaf(e[j], e[j], sumsq);
                }
                const float m = fmaxf(sqrtf(sumsq), 1e-12f);
                float h = 0.0f;
                #pragma unroll
                for (int j = 0; j < NIMG; ++j) {
                    const float en = e[j] / m;
                    if (en > 0.35f) h = fmaf(e[j], xa[j][q], h);
                }
                ho[q] = h;
            }
            const float4 ov = {ho[0], ho[1], ho[2], ho[3]};
            *reinterpret_cast<float4*>(&out[(size_t)i * PT + base]) = ov;
        }
    }
}

extern "C" void kernel_launch(void* const* d_in, const int* in_sizes, int n_in,
                              void* d_out, int out_size, void* d_ws, size_t ws_size,
                              hipStream_t stream) {
    const float* x    = (const float*)d_in[0];
    const float* w    = (const float*)d_in[1];
    const float* bias = (const float*)d_in[2];
    float* out = (float*)d_out;

    // grid.x = 64 p-slices, grid.y = 8 d-tiles; linear wgid%8 == x%8 pins all
    // 8 d-tiles sharing a p-slice of x to one XCD (L2 reuse of x reads).
    dim3 g(HWP / BP, CCH / BD);   // 64 x 8 = 512 blocks, 2 per CU
    fused_all<<<g, 256, 0, stream>>>(x, w, bias, out);
}